// Round 2
// baseline (2464.060 us; speedup 1.0000x reference)
//
#include <hip/hip_runtime.h>
#include <hip/hip_bf16.h>
#include <cstdint>
#include <cstddef>

#define DEVI __device__ __forceinline__

typedef __attribute__((ext_vector_type(4))) float f32x4;
typedef __attribute__((ext_vector_type(8))) short s16x8;
typedef __attribute__((ext_vector_type(4))) short s16x4;

constexpr int TB = 16;         // batch
constexpr int TT = 2048;       // time
constexpr int TD = 512;        // model dim
constexpr int TDFF = 2048;     // ffn dim
constexpr int NTOK = TB * TT;  // 32768
constexpr int KW = 31;         // conv kernel width
constexpr int CH = 8192;       // M-chunk (4 whole batches)
constexpr int NCHUNK = NTOK / CH;

DEVI float b2f(unsigned short u) {
  union { float f; unsigned v; } x; x.v = ((unsigned)u) << 16; return x.f;
}
DEVI unsigned short f2bfb(float f) {
  __hip_bfloat16 h = __float2bfloat16(f);
  return __builtin_bit_cast(unsigned short, h);
}
DEVI float sigm(float x) { return 1.0f / (1.0f + __expf(-x)); }

DEVI void gload_lds16(const void* g, void* l) {
  __builtin_amdgcn_global_load_lds(
      (__attribute__((address_space(1))) unsigned int*)g,
      (__attribute__((address_space(3))) unsigned int*)l, 16, 0, 0);
}

// D = A*B + D, 16x16x32 bf16. Inline asm; in-loop dependent MFMAs are >=16
// instructions apart (hazard-safe); epilogue protected by s_nops.
DEVI f32x4 mfma_bf16(s16x8 a, s16x8 b, f32x4 c) {
  asm("v_mfma_f32_16x16x32_bf16 %0, %1, %2, %0" : "+v"(c) : "v"(a), "v"(b));
  return c;
}

// ---------------------------------------------------------------------------
// GEMM: C(Mrows,N) = A(.,K) x B(N,K)^T + bias  (A,B bf16 row-major)
// EPI 0: out = bf16(acc+bias)
// EPI 1: out = bf16(swish(acc+bias))
// EPI 2: resout = resin + rscale*(acc+bias)   (f32; resin may alias resout)
// 128x128 tile, BK=64, 256 thr (4 waves 2x2), global_load_lds width-16 staging.
// ---------------------------------------------------------------------------
template<int EPI>
__global__ __launch_bounds__(256)
void gemm_bt(const __hip_bfloat16* __restrict__ A, const __hip_bfloat16* __restrict__ Bw,
             const float* __restrict__ bias, const float* resin, float* resout,
             __hip_bfloat16* __restrict__ outbf, int N, int K, float rscale)
{
  __shared__ alignas(16) short lds[2 * 128 * 64];   // A tile then B tile, 16KB each
  short* As = lds;
  short* Bs = lds + 128 * 64;

  const int tid = threadIdx.x;
  const int w = tid >> 6, l = tid & 63;
  const int row0 = blockIdx.x * 128;
  const int col0 = blockIdx.y * 128;

  // staging: each wave's 64 lanes write LDS base + lane*16B -> 8 rows of 64 bf16
  const int srow = w * 8 + (l >> 3);
  const int scol = (l & 7) * 8;

  f32x4 acc[4][4];
#pragma unroll
  for (int m = 0; m < 4; ++m)
#pragma unroll
    for (int n = 0; n < 4; ++n)
      acc[m][n] = f32x4{0.f, 0.f, 0.f, 0.f};

  const int wr = (w >> 1) * 64, wc = (w & 1) * 64;

  for (int k0 = 0; k0 < K; k0 += 64) {
    __syncthreads();   // prior-iter ds_reads done before overwrite
#pragma unroll
    for (int it = 0; it < 4; ++it) {
      gload_lds16(A  + (size_t)(row0 + it * 32 + srow) * K + k0 + scol,
                  (char*)As + (it * 32 + w * 8) * 128);
      gload_lds16(Bw + (size_t)(col0 + it * 32 + srow) * K + k0 + scol,
                  (char*)Bs + (it * 32 + w * 8) * 128);
    }
    __syncthreads();   // vmcnt(0)+lgkmcnt(0) drained before barrier -> LDS visible
#pragma unroll
    for (int ks = 0; ks < 2; ++ks) {
      const int ko = ks * 64 + (l >> 4) * 16;   // byte offset in 128B row
      s16x8 af[4], bfr[4];
#pragma unroll
      for (int m = 0; m < 4; ++m)
        af[m] = *(const s16x8*)((const char*)As + (wr + m * 16 + (l & 15)) * 128 + ko);
#pragma unroll
      for (int n = 0; n < 4; ++n)
        bfr[n] = *(const s16x8*)((const char*)Bs + (wc + n * 16 + (l & 15)) * 128 + ko);
#pragma unroll
      for (int m = 0; m < 4; ++m)
#pragma unroll
        for (int n = 0; n < 4; ++n)
          acc[m][n] = mfma_bf16(af[m], bfr[n], acc[m][n]);
    }
  }

  asm volatile("s_nop 7\n\ts_nop 7");   // MFMA->VALU read hazard guard

#pragma unroll
  for (int n = 0; n < 4; ++n) {
    const int gcol = col0 + wc + n * 16 + (l & 15);
    const float bv = bias[gcol];
#pragma unroll
    for (int m = 0; m < 4; ++m) {
      const int grow0 = row0 + wr + m * 16 + (l >> 4) * 4;
#pragma unroll
      for (int r = 0; r < 4; ++r) {
        const size_t idx = (size_t)(grow0 + r) * N + gcol;
        const float v = acc[m][n][r] + bv;
        if constexpr (EPI == 0) {
          outbf[idx] = __float2bfloat16(v);
        } else if constexpr (EPI == 1) {
          outbf[idx] = __float2bfloat16(v * sigm(v));
        } else {
          resout[idx] = resin[idx] + rscale * v;
        }
      }
    }
  }
}

// ---------------------------------------------------------------------------
// LayerNorm over D=512. One wave per token, 4 tokens/block.
// OUTF32=0 -> bf16 out, OUTF32=1 -> f32 out (may be in-place on x).
// ---------------------------------------------------------------------------
template<int OUTF32>
__global__ __launch_bounds__(256)
void ln_k(const float* __restrict__ x, const float* __restrict__ g,
          const float* __restrict__ b, void* __restrict__ outp)
{
  const int w = threadIdx.x >> 6, l = threadIdx.x & 63;
  const size_t tok = (size_t)blockIdx.x * 4 + w;
  const float4* xr = (const float4*)(x + tok * TD);
  const float4 v0 = xr[l], v1 = xr[64 + l];
  float s = v0.x + v0.y + v0.z + v0.w + v1.x + v1.y + v1.z + v1.w;
  float q = v0.x * v0.x + v0.y * v0.y + v0.z * v0.z + v0.w * v0.w
          + v1.x * v1.x + v1.y * v1.y + v1.z * v1.z + v1.w * v1.w;
#pragma unroll
  for (int o = 32; o > 0; o >>= 1) { s += __shfl_xor(s, o); q += __shfl_xor(q, o); }
  const float mean = s * (1.f / TD);
  const float rs = rsqrtf(q * (1.f / TD) - mean * mean + 1e-5f);
  const float4 g0 = ((const float4*)g)[l], g1 = ((const float4*)g)[64 + l];
  const float4 b0 = ((const float4*)b)[l], b1 = ((const float4*)b)[64 + l];
  const float o0 = (v0.x - mean) * rs * g0.x + b0.x;
  const float o1 = (v0.y - mean) * rs * g0.y + b0.y;
  const float o2 = (v0.z - mean) * rs * g0.z + b0.z;
  const float o3 = (v0.w - mean) * rs * g0.w + b0.w;
  const float o4 = (v1.x - mean) * rs * g1.x + b1.x;
  const float o5 = (v1.y - mean) * rs * g1.y + b1.y;
  const float o6 = (v1.z - mean) * rs * g1.z + b1.z;
  const float o7 = (v1.w - mean) * rs * g1.w + b1.w;
  if constexpr (OUTF32) {
    float4* out = (float4*)outp + tok * 128;
    out[l]      = make_float4(o0, o1, o2, o3);
    out[64 + l] = make_float4(o4, o5, o6, o7);
  } else {
    s16x4 p0{(short)f2bfb(o0), (short)f2bfb(o1), (short)f2bfb(o2), (short)f2bfb(o3)};
    s16x4 p1{(short)f2bfb(o4), (short)f2bfb(o5), (short)f2bfb(o6), (short)f2bfb(o7)};
    ((s16x4*)outp)[tok * 128 + l]      = p0;
    ((s16x4*)outp)[tok * 128 + 64 + l] = p1;
  }
}

// ---------------------------------------------------------------------------
// Hydra pass1 (per M-chunk of 4 batches): qn = q/|q| (bf16, in-place rows);
// kvpart[(b,ch)] = sum over chunk tokens of (k/|k|)*v. Deterministic order.
// grid (4 batches, 32 chunks of 64 tokens), block 256 (4 waves x 16 tokens).
// ---------------------------------------------------------------------------
__global__ __launch_bounds__(256)
void hydra_pass1(const __hip_bfloat16* __restrict__ qkv,   // chunk-local rows
                 __hip_bfloat16* __restrict__ qn,           // chunk-local rows
                 float* __restrict__ kvpart, int b0)
{
  const int bl = blockIdx.x, ch = blockIdx.y;
  const int w = threadIdx.x >> 6, l = threadIdx.x & 63;
  float kvp[8] = {0.f, 0.f, 0.f, 0.f, 0.f, 0.f, 0.f, 0.f};
  __shared__ float part[4][512];

  for (int it = 0; it < 16; ++it) {
    const int t = ch * 64 + w * 16 + it;
    const short* row = (const short*)qkv + ((size_t)bl * TT + t) * (3 * TD);
    const s16x8 q8 = *(const s16x8*)(row + 8 * l);
    const s16x8 k8 = *(const s16x8*)(row + TD + 8 * l);
    const s16x8 v8 = *(const s16x8*)(row + 2 * TD + 8 * l);
    float qf[8], kf[8], vf[8];
    float sq = 0.f, sk = 0.f;
#pragma unroll
    for (int j = 0; j < 8; ++j) {
      qf[j] = b2f((unsigned short)q8[j]); sq += qf[j] * qf[j];
      kf[j] = b2f((unsigned short)k8[j]); sk += kf[j] * kf[j];
      vf[j] = b2f((unsigned short)v8[j]);
    }
#pragma unroll
    for (int o = 32; o > 0; o >>= 1) { sq += __shfl_xor(sq, o); sk += __shfl_xor(sk, o); }
    const float rq = rsqrtf(sq), rk = rsqrtf(sk);
    s16x8 r;
#pragma unroll
    for (int j = 0; j < 8; ++j) {
      r[j] = (short)f2bfb(qf[j] * rq);
      kvp[j] += kf[j] * rk * vf[j];
    }
    *(s16x8*)((short*)qn + ((size_t)bl * TT + t) * TD + 8 * l) = r;
  }
#pragma unroll
  for (int j = 0; j < 8; ++j) part[w][8 * l + j] = kvp[j];
  __syncthreads();
#pragma unroll
  for (int hh = 0; hh < 2; ++hh) {
    const int d = threadIdx.x + hh * 256;
    kvpart[((size_t)(b0 + bl) * 32 + ch) * TD + d]
        = part[0][d] + part[1][d] + part[2][d] + part[3][d];
  }
}

__global__ __launch_bounds__(256)
void kv_reduce(const float* __restrict__ kvpart, float* __restrict__ kv)
{
  const int i = blockIdx.x * 256 + threadIdx.x;   // 16*512
  const int b = i >> 9, d = i & 511;
  float s = 0.f;
#pragma unroll
  for (int ch = 0; ch < 32; ++ch) s += kvpart[((size_t)b * 32 + ch) * TD + d];
  kv[i] = s;
}

// qn *= kv[b]  (in place, bf16, full M)
__global__ __launch_bounds__(256)
void qscale_k(__hip_bfloat16* qn, const float* __restrict__ kv)
{
  const size_t i = ((size_t)blockIdx.x * 256 + threadIdx.x) * 8;
  const size_t tok = i >> 9;
  const int d = (int)(i & 511);
  const int b = (int)(tok >> 11);
  const s16x8 v = *(const s16x8*)((const short*)qn + i);
  const float4 k0 = *(const float4*)(kv + b * 512 + d);
  const float4 k1 = *(const float4*)(kv + b * 512 + d + 4);
  s16x8 r;
  r[0] = (short)f2bfb(b2f((unsigned short)v[0]) * k0.x);
  r[1] = (short)f2bfb(b2f((unsigned short)v[1]) * k0.y);
  r[2] = (short)f2bfb(b2f((unsigned short)v[2]) * k0.z);
  r[3] = (short)f2bfb(b2f((unsigned short)v[3]) * k0.w);
  r[4] = (short)f2bfb(b2f((unsigned short)v[4]) * k1.x);
  r[5] = (short)f2bfb(b2f((unsigned short)v[5]) * k1.y);
  r[6] = (short)f2bfb(b2f((unsigned short)v[6]) * k1.z);
  r[7] = (short)f2bfb(b2f((unsigned short)v[7]) * k1.w);
  *(s16x8*)((short*)qn + i) = r;
}

// GLU over a chunk: out[tok][d] = c[tok][d] * sigmoid(c[tok][512+d])
__global__ __launch_bounds__(256)
void glu_k(const __hip_bfloat16* __restrict__ c, __hip_bfloat16* __restrict__ out)
{
  const size_t i = ((size_t)blockIdx.x * 256 + threadIdx.x) * 8;
  const size_t tok = i >> 9;
  const int d = (int)(i & 511);
  const short* row = (const short*)c + tok * 1024;
  const s16x8 a8 = *(const s16x8*)(row + d);
  const s16x8 g8 = *(const s16x8*)(row + 512 + d);
  s16x8 r;
#pragma unroll
  for (int j = 0; j < 8; ++j) {
    const float a = b2f((unsigned short)a8[j]);
    const float g = b2f((unsigned short)g8[j]);
    r[j] = (short)f2bfb(a * sigm(g));
  }
  *(s16x8*)((short*)out + i) = r;
}

// depthwise conv(K=31, pad 15 over T) + bias + LN(lncn) + swish -> bf16
// one block per token; thread owns channels d and d+256.
__global__ __launch_bounds__(256)
void conv_ln_swish(const __hip_bfloat16* __restrict__ gin, const float* __restrict__ dww,
                   const float* __restrict__ dwb, const float* __restrict__ lg,
                   const float* __restrict__ lb, __hip_bfloat16* __restrict__ out)
{
  const int tok = blockIdx.x;
  const int t = tok & (TT - 1);
  const int tid = threadIdx.x;
  const short* base = (const short*)gin + (size_t)tok * TD;
  float acc0 = 0.f, acc1 = 0.f;
#pragma unroll
  for (int hh = 0; hh < 2; ++hh) {
    const int d = tid + hh * 256;
    float a = dwb[d];
    for (int j = 0; j < KW; ++j) {
      const int tt = t + j - 15;
      if (tt >= 0 && tt < TT)
        a += b2f((unsigned short)base[(ptrdiff_t)(j - 15) * TD + d]) * dww[d * KW + j];
    }
    if (hh == 0) acc0 = a; else acc1 = a;
  }
  float s = acc0 + acc1, q = acc0 * acc0 + acc1 * acc1;
#pragma unroll
  for (int o = 32; o > 0; o >>= 1) { s += __shfl_xor(s, o); q += __shfl_xor(q, o); }
  __shared__ float ss[4], sq2[4];
  const int w = tid >> 6, l = tid & 63;
  if (l == 0) { ss[w] = s; sq2[w] = q; }
  __syncthreads();
  s = ss[0] + ss[1] + ss[2] + ss[3];
  q = sq2[0] + sq2[1] + sq2[2] + sq2[3];
  const float mean = s * (1.f / TD);
  const float rs = rsqrtf(q * (1.f / TD) - mean * mean + 1e-5f);
#pragma unroll
  for (int hh = 0; hh < 2; ++hh) {
    const int d = tid + hh * 256;
    const float a = (hh == 0) ? acc0 : acc1;
    const float y = (a - mean) * rs * lg[d] + lb[d];
    out[(size_t)tok * TD + d] = __float2bfloat16(y * sigm(y));
  }
}

// f32 -> bf16 cast, 8 elems/thread
__global__ __launch_bounds__(256)
void cast8_k(const float* __restrict__ in, __hip_bfloat16* __restrict__ out, int n8)
{
  const int i = blockIdx.x * 256 + threadIdx.x;
  if (i >= n8) return;
  const float4 a = ((const float4*)in)[2 * i];
  const float4 b = ((const float4*)in)[2 * i + 1];
  s16x8 r;
  r[0] = (short)f2bfb(a.x); r[1] = (short)f2bfb(a.y);
  r[2] = (short)f2bfb(a.z); r[3] = (short)f2bfb(a.w);
  r[4] = (short)f2bfb(b.x); r[5] = (short)f2bfb(b.y);
  r[6] = (short)f2bfb(b.z); r[7] = (short)f2bfb(b.w);
  ((s16x8*)out)[i] = r;
}

extern "C" void kernel_launch(void* const* d_in, const int* in_sizes, int n_in,
                              void* d_out, int out_size, void* d_ws, size_t ws_size,
                              hipStream_t stream)
{
  const float* x      = (const float*)d_in[0];
  const float* ln1_g  = (const float*)d_in[1];
  const float* ln1_b  = (const float*)d_in[2];
  const float* ff1_w1 = (const float*)d_in[3];
  const float* ff1_b1 = (const float*)d_in[4];
  const float* ff1_w2 = (const float*)d_in[5];
  const float* ff1_b2 = (const float*)d_in[6];
  const float* lna_g  = (const float*)d_in[7];
  const float* lna_b  = (const float*)d_in[8];
  const float* qkv_w  = (const float*)d_in[9];
  const float* qkv_b  = (const float*)d_in[10];
  const float* aow    = (const float*)d_in[11];
  const float* aob    = (const float*)d_in[12];
  const float* lnc_g  = (const float*)d_in[13];
  const float* lnc_b  = (const float*)d_in[14];
  const float* pw1_w  = (const float*)d_in[15];
  const float* pw1_b  = (const float*)d_in[16];
  const float* dw_w   = (const float*)d_in[17];
  const float* dw_b   = (const float*)d_in[18];
  const float* lncn_g = (const float*)d_in[19];
  const float* lncn_b = (const float*)d_in[20];
  const float* pw2_w  = (const float*)d_in[21];
  const float* pw2_b  = (const float*)d_in[22];
  const float* ln2_g  = (const float*)d_in[23];
  const float* ln2_b  = (const float*)d_in[24];
  const float* ff2_w1 = (const float*)d_in[25];
  const float* ff2_b1 = (const float*)d_in[26];
  const float* ff2_w2 = (const float*)d_in[27];
  const float* ff2_b2 = (const float*)d_in[28];
  const float* lno_g  = (const float*)d_in[29];
  const float* lno_b  = (const float*)d_in[30];
  (void)in_sizes; (void)n_in; (void)out_size;

  // Residual stream lives in d_out (f32, exactly B*T*D); final LN is in-place.
  float* res = (float*)d_out;

  char* ws = (char*)d_ws;
  size_t off = 0;
  auto alloc = [&](size_t bytes) {
    char* p = ws + off;
    off = (off + bytes + 255) & ~(size_t)255;
    return p;
  };

  __hip_bfloat16* wff1a = (__hip_bfloat16*)alloc((size_t)TDFF * TD * 2);
  __hip_bfloat16* wff1b = (__hip_bfloat16*)alloc((size_t)TD * TDFF * 2);
  __hip_bfloat16* wqkv  = (__hip_bfloat16*)alloc((size_t)3 * TD * TD * 2);
  __hip_bfloat16* wao   = (__hip_bfloat16*)alloc((size_t)TD * TD * 2);
  __hip_bfloat16* wpw1  = (__hip_bfloat16*)alloc((size_t)2 * TD * TD * 2);
  __hip_bfloat16* wpw2  = (__hip_bfloat16*)alloc((size_t)TD * TD * 2);
  __hip_bfloat16* wff2a = (__hip_bfloat16*)alloc((size_t)TDFF * TD * 2);
  __hip_bfloat16* wff2b = (__hip_bfloat16*)alloc((size_t)TD * TDFF * 2);
  __hip_bfloat16* h     = (__hip_bfloat16*)alloc((size_t)NTOK * TD * 2);     // 32MB
  __hip_bfloat16* big   = (__hip_bfloat16*)alloc((size_t)CH * TDFF * 2);     // 32MB chunk buf
  float*          kv    = (float*)alloc((size_t)TB * TD * 4);
  float*          kvp   = (float*)alloc((size_t)TB * 32 * TD * 4);

  if (ws_size < off) return;   // interpretable failure instead of a page fault

  const dim3 blk(256);
  const int M = NTOK;

  auto cast = [&](const float* src, __hip_bfloat16* dst, int n) {
    cast8_k<<<(n / 8 + 255) / 256, blk, 0, stream>>>(src, dst, n / 8);
  };
  cast(ff1_w1, wff1a, TDFF * TD);
  cast(ff1_w2, wff1b, TD * TDFF);
  cast(qkv_w,  wqkv,  3 * TD * TD);
  cast(aow,    wao,   TD * TD);
  cast(pw1_w,  wpw1,  2 * TD * TD);
  cast(pw2_w,  wpw2,  TD * TD);
  cast(ff2_w1, wff2a, TDFF * TD);
  cast(ff2_w2, wff2b, TD * TDFF);

  const dim3 gchunk(CH / 128, TDFF / 128);   // (64,16) for N=2048

  // ---- FF1 (half-step): res = x + 0.5*ffn(ln1(x)) ----
  ln_k<0><<<M / 4, blk, 0, stream>>>(x, ln1_g, ln1_b, h);
  for (int c = 0; c < NCHUNK; ++c) {
    const size_t o5 = (size_t)c * CH * TD;      // token-major f32/bf16 offset (D)
    gemm_bt<1><<<dim3(CH / 128, TDFF / 128), blk, 0, stream>>>(
        h + o5, wff1a, ff1_b1, nullptr, nullptr, big, TDFF, TD, 0.f);
    gemm_bt<2><<<dim3(CH / 128, TD / 128), blk, 0, stream>>>(
        big, wff1b, ff1_b2, x + o5, res + o5, nullptr, TD, TDFF, 0.5f);
  }

  // ---- Hydra attention ----
  ln_k<0><<<M / 4, blk, 0, stream>>>(res, lna_g, lna_b, h);
  for (int c = 0; c < NCHUNK; ++c) {
    const size_t o5 = (size_t)c * CH * TD;
    gemm_bt<0><<<dim3(CH / 128, 3 * TD / 128), blk, 0, stream>>>(
        h + o5, wqkv, qkv_b, nullptr, nullptr, big, 3 * TD, TD, 0.f);
    hydra_pass1<<<dim3(CH / TT, 32), blk, 0, stream>>>(big, h + o5, kvp, c * (CH / TT));
  }
  kv_reduce<<<(TB * TD) / 256, blk, 0, stream>>>(kvp, kv);
  qscale_k<<<(M * (TD / 8)) / 256, blk, 0, stream>>>(h, kv);
  gemm_bt<2><<<dim3(M / 128, TD / 128), blk, 0, stream>>>(
      h, wao, aob, res, res, nullptr, TD, TD, 1.f);

  // ---- Conv module ----
  ln_k<0><<<M / 4, blk, 0, stream>>>(res, lnc_g, lnc_b, h);
  for (int c = 0; c < NCHUNK; ++c) {
    const size_t o5 = (size_t)c * CH * TD;
    gemm_bt<0><<<dim3(CH / 128, 2 * TD / 128), blk, 0, stream>>>(
        h + o5, wpw1, pw1_b, nullptr, nullptr, big, 2 * TD, TD, 0.f);
    glu_k<<<(CH * (TD / 8)) / 256, blk, 0, stream>>>(big, h + o5);
  }
  // conv input h (full M), output into big (M x D bf16 = same 32MB)
  conv_ln_swish<<<M, blk, 0, stream>>>(h, dw_w, dw_b, lncn_g, lncn_b, big);
  gemm_bt<2><<<dim3(M / 128, TD / 128), blk, 0, stream>>>(
      big, wpw2, pw2_b, res, res, nullptr, TD, TD, 1.f);

  // ---- FF2 (half-step) ----
  ln_k<0><<<M / 4, blk, 0, stream>>>(res, ln2_g, ln2_b, h);
  for (int c = 0; c < NCHUNK; ++c) {
    const size_t o5 = (size_t)c * CH * TD;
    gemm_bt<1><<<dim3(CH / 128, TDFF / 128), blk, 0, stream>>>(
        h + o5, wff2a, ff2_b1, nullptr, nullptr, big, TDFF, TD, 0.f);
    gemm_bt<2><<<dim3(CH / 128, TD / 128), blk, 0, stream>>>(
        big, wff2b, ff2_b2, res + o5, res + o5, nullptr, TD, TDFF, 0.5f);
  }

  // ---- final LN (in-place on d_out) ----
  ln_k<1><<<M / 4, blk, 0, stream>>>(res, lno_g, lno_b, res);
}

// Round 3
// 1225.433 us; speedup vs baseline: 2.0108x; 2.0108x over previous
//
#include <hip/hip_runtime.h>
#include <hip/hip_bf16.h>
#include <cstdint>
#include <cstddef>

#define DEVI __device__ __forceinline__

typedef __attribute__((ext_vector_type(4))) float f32x4;
typedef __attribute__((ext_vector_type(8))) short s16x8;
typedef __attribute__((ext_vector_type(4))) short s16x4;

constexpr int TB = 16;         // batch
constexpr int TT = 2048;       // time
constexpr int TD = 512;        // model dim
constexpr int TDFF = 2048;     // ffn dim
constexpr int NTOK = TB * TT;  // 32768
constexpr int KW = 31;         // conv kernel width
constexpr int CH = 8192;       // M-chunk (4 whole batches)
constexpr int NCHUNK = NTOK / CH;
constexpr int CT = 8;          // conv: tokens per block

DEVI float b2f(unsigned short u) {
  union { float f; unsigned v; } x; x.v = ((unsigned)u) << 16; return x.f;
}
DEVI unsigned short f2bfb(float f) {
  __hip_bfloat16 h = __float2bfloat16(f);
  return __builtin_bit_cast(unsigned short, h);
}
DEVI float sigm(float x) { return 1.0f / (1.0f + __expf(-x)); }

DEVI void gload_lds16(const void* g, void* l) {
  __builtin_amdgcn_global_load_lds(
      (__attribute__((address_space(1))) unsigned int*)g,
      (__attribute__((address_space(3))) unsigned int*)l, 16, 0, 0);
}

// D = A*B + D, 16x16x32 bf16. Inline asm; in-loop dependent MFMAs are >=16
// instructions apart (hazard-safe); epilogue protected by s_nops.
DEVI f32x4 mfma_bf16(s16x8 a, s16x8 b, f32x4 c) {
  asm("v_mfma_f32_16x16x32_bf16 %0, %1, %2, %0" : "+v"(c) : "v"(a), "v"(b));
  return c;
}

// ---------------------------------------------------------------------------
// GEMM: C(Mrows,N) = A(.,K) x B(N,K)^T + bias  (A,B bf16 row-major)
// EPI 0: out = bf16(acc+bias)
// EPI 1: out = bf16(swish(acc+bias))
// EPI 2: resout = resin + rscale*(acc+bias)   (f32; resin may alias resout)
// 128x128 tile, BK=64, 256 thr (4 waves 2x2), global_load_lds width-16 staging.
// ---------------------------------------------------------------------------
template<int EPI>
__global__ __launch_bounds__(256)
void gemm_bt(const __hip_bfloat16* __restrict__ A, const __hip_bfloat16* __restrict__ Bw,
             const float* __restrict__ bias, const float* resin, float* resout,
             __hip_bfloat16* __restrict__ outbf, int N, int K, float rscale)
{
  __shared__ alignas(16) short lds[2 * 128 * 64];   // A tile then B tile, 16KB each
  short* As = lds;
  short* Bs = lds + 128 * 64;

  const int tid = threadIdx.x;
  const int w = tid >> 6, l = tid & 63;
  const int row0 = blockIdx.x * 128;
  const int col0 = blockIdx.y * 128;

  // staging: each wave's 64 lanes write LDS base + lane*16B -> 8 rows of 64 bf16
  const int srow = w * 8 + (l >> 3);
  const int scol = (l & 7) * 8;

  f32x4 acc[4][4];
#pragma unroll
  for (int m = 0; m < 4; ++m)
#pragma unroll
    for (int n = 0; n < 4; ++n)
      acc[m][n] = f32x4{0.f, 0.f, 0.f, 0.f};

  const int wr = (w >> 1) * 64, wc = (w & 1) * 64;

  for (int k0 = 0; k0 < K; k0 += 64) {
    __syncthreads();   // prior-iter ds_reads done before overwrite
#pragma unroll
    for (int it = 0; it < 4; ++it) {
      gload_lds16(A  + (size_t)(row0 + it * 32 + srow) * K + k0 + scol,
                  (char*)As + (it * 32 + w * 8) * 128);
      gload_lds16(Bw + (size_t)(col0 + it * 32 + srow) * K + k0 + scol,
                  (char*)Bs + (it * 32 + w * 8) * 128);
    }
    __syncthreads();   // vmcnt(0)+lgkmcnt(0) drained before barrier -> LDS visible
#pragma unroll
    for (int ks = 0; ks < 2; ++ks) {
      const int ko = ks * 64 + (l >> 4) * 16;   // byte offset in 128B row
      s16x8 af[4], bfr[4];
#pragma unroll
      for (int m = 0; m < 4; ++m)
        af[m] = *(const s16x8*)((const char*)As + (wr + m * 16 + (l & 15)) * 128 + ko);
#pragma unroll
      for (int n = 0; n < 4; ++n)
        bfr[n] = *(const s16x8*)((const char*)Bs + (wc + n * 16 + (l & 15)) * 128 + ko);
#pragma unroll
      for (int m = 0; m < 4; ++m)
#pragma unroll
        for (int n = 0; n < 4; ++n)
          acc[m][n] = mfma_bf16(af[m], bfr[n], acc[m][n]);
    }
  }

  asm volatile("s_nop 7\n\ts_nop 7");   // MFMA->VALU read hazard guard

#pragma unroll
  for (int n = 0; n < 4; ++n) {
    const int gcol = col0 + wc + n * 16 + (l & 15);
    const float bv = bias[gcol];
#pragma unroll
    for (int m = 0; m < 4; ++m) {
      const int grow0 = row0 + wr + m * 16 + (l >> 4) * 4;
#pragma unroll
      for (int r = 0; r < 4; ++r) {
        const size_t idx = (size_t)(grow0 + r) * N + gcol;
        const float v = acc[m][n][r] + bv;
        if constexpr (EPI == 0) {
          outbf[idx] = __float2bfloat16(v);
        } else if constexpr (EPI == 1) {
          outbf[idx] = __float2bfloat16(v * sigm(v));
        } else {
          resout[idx] = resin[idx] + rscale * v;
        }
      }
    }
  }
}

// ---------------------------------------------------------------------------
// LayerNorm over D=512. One wave per token, 4 tokens/block.
// OUTF32=0 -> bf16 out, OUTF32=1 -> f32 out (may be in-place on x).
// ---------------------------------------------------------------------------
template<int OUTF32>
__global__ __launch_bounds__(256)
void ln_k(const float* __restrict__ x, const float* __restrict__ g,
          const float* __restrict__ b, void* __restrict__ outp)
{
  const int w = threadIdx.x >> 6, l = threadIdx.x & 63;
  const size_t tok = (size_t)blockIdx.x * 4 + w;
  const float4* xr = (const float4*)(x + tok * TD);
  const float4 v0 = xr[l], v1 = xr[64 + l];
  float s = v0.x + v0.y + v0.z + v0.w + v1.x + v1.y + v1.z + v1.w;
  float q = v0.x * v0.x + v0.y * v0.y + v0.z * v0.z + v0.w * v0.w
          + v1.x * v1.x + v1.y * v1.y + v1.z * v1.z + v1.w * v1.w;
#pragma unroll
  for (int o = 32; o > 0; o >>= 1) { s += __shfl_xor(s, o); q += __shfl_xor(q, o); }
  const float mean = s * (1.f / TD);
  const float rs = rsqrtf(q * (1.f / TD) - mean * mean + 1e-5f);
  const float4 g0 = ((const float4*)g)[l], g1 = ((const float4*)g)[64 + l];
  const float4 b0 = ((const float4*)b)[l], b1 = ((const float4*)b)[64 + l];
  const float o0 = (v0.x - mean) * rs * g0.x + b0.x;
  const float o1 = (v0.y - mean) * rs * g0.y + b0.y;
  const float o2 = (v0.z - mean) * rs * g0.z + b0.z;
  const float o3 = (v0.w - mean) * rs * g0.w + b0.w;
  const float o4 = (v1.x - mean) * rs * g1.x + b1.x;
  const float o5 = (v1.y - mean) * rs * g1.y + b1.y;
  const float o6 = (v1.z - mean) * rs * g1.z + b1.z;
  const float o7 = (v1.w - mean) * rs * g1.w + b1.w;
  if constexpr (OUTF32) {
    float4* out = (float4*)outp + tok * 128;
    out[l]      = make_float4(o0, o1, o2, o3);
    out[64 + l] = make_float4(o4, o5, o6, o7);
  } else {
    s16x4 p0{(short)f2bfb(o0), (short)f2bfb(o1), (short)f2bfb(o2), (short)f2bfb(o3)};
    s16x4 p1{(short)f2bfb(o4), (short)f2bfb(o5), (short)f2bfb(o6), (short)f2bfb(o7)};
    ((s16x4*)outp)[tok * 128 + l]      = p0;
    ((s16x4*)outp)[tok * 128 + 64 + l] = p1;
  }
}

// ---------------------------------------------------------------------------
// Hydra pass1 (per M-chunk of 4 batches): qn = q/|q| (bf16, in-place rows);
// kvpart[(b,ch)] = sum over chunk tokens of (k/|k|)*v. Deterministic order.
// ---------------------------------------------------------------------------
__global__ __launch_bounds__(256)
void hydra_pass1(const __hip_bfloat16* __restrict__ qkv,   // chunk-local rows
                 __hip_bfloat16* __restrict__ qn,           // chunk-local rows
                 float* __restrict__ kvpart, int b0)
{
  const int bl = blockIdx.x, ch = blockIdx.y;
  const int w = threadIdx.x >> 6, l = threadIdx.x & 63;
  float kvp[8] = {0.f, 0.f, 0.f, 0.f, 0.f, 0.f, 0.f, 0.f};
  __shared__ float part[4][512];

  for (int it = 0; it < 16; ++it) {
    const int t = ch * 64 + w * 16 + it;
    const short* row = (const short*)qkv + ((size_t)bl * TT + t) * (3 * TD);
    const s16x8 q8 = *(const s16x8*)(row + 8 * l);
    const s16x8 k8 = *(const s16x8*)(row + TD + 8 * l);
    const s16x8 v8 = *(const s16x8*)(row + 2 * TD + 8 * l);
    float qf[8], kf[8], vf[8];
    float sq = 0.f, sk = 0.f;
#pragma unroll
    for (int j = 0; j < 8; ++j) {
      qf[j] = b2f((unsigned short)q8[j]); sq += qf[j] * qf[j];
      kf[j] = b2f((unsigned short)k8[j]); sk += kf[j] * kf[j];
      vf[j] = b2f((unsigned short)v8[j]);
    }
#pragma unroll
    for (int o = 32; o > 0; o >>= 1) { sq += __shfl_xor(sq, o); sk += __shfl_xor(sk, o); }
    const float rq = rsqrtf(sq), rk = rsqrtf(sk);
    s16x8 r;
#pragma unroll
    for (int j = 0; j < 8; ++j) {
      r[j] = (short)f2bfb(qf[j] * rq);
      kvp[j] += kf[j] * rk * vf[j];
    }
    *(s16x8*)((short*)qn + ((size_t)bl * TT + t) * TD + 8 * l) = r;
  }
#pragma unroll
  for (int j = 0; j < 8; ++j) part[w][8 * l + j] = kvp[j];
  __syncthreads();
#pragma unroll
  for (int hh = 0; hh < 2; ++hh) {
    const int d = threadIdx.x + hh * 256;
    kvpart[((size_t)(b0 + bl) * 32 + ch) * TD + d]
        = part[0][d] + part[1][d] + part[2][d] + part[3][d];
  }
}

__global__ __launch_bounds__(256)
void kv_reduce(const float* __restrict__ kvpart, float* __restrict__ kv)
{
  const int i = blockIdx.x * 256 + threadIdx.x;   // 16*512
  const int b = i >> 9, d = i & 511;
  float s = 0.f;
#pragma unroll
  for (int ch = 0; ch < 32; ++ch) s += kvpart[((size_t)b * 32 + ch) * TD + d];
  kv[i] = s;
}

// qn *= kv[b]  (in place, bf16, full M)
__global__ __launch_bounds__(256)
void qscale_k(__hip_bfloat16* qn, const float* __restrict__ kv)
{
  const size_t i = ((size_t)blockIdx.x * 256 + threadIdx.x) * 8;
  const size_t tok = i >> 9;
  const int d = (int)(i & 511);
  const int b = (int)(tok >> 11);
  const s16x8 v = *(const s16x8*)((const short*)qn + i);
  const float4 k0 = *(const float4*)(kv + b * 512 + d);
  const float4 k1 = *(const float4*)(kv + b * 512 + d + 4);
  s16x8 r;
  r[0] = (short)f2bfb(b2f((unsigned short)v[0]) * k0.x);
  r[1] = (short)f2bfb(b2f((unsigned short)v[1]) * k0.y);
  r[2] = (short)f2bfb(b2f((unsigned short)v[2]) * k0.z);
  r[3] = (short)f2bfb(b2f((unsigned short)v[3]) * k0.w);
  r[4] = (short)f2bfb(b2f((unsigned short)v[4]) * k1.x);
  r[5] = (short)f2bfb(b2f((unsigned short)v[5]) * k1.y);
  r[6] = (short)f2bfb(b2f((unsigned short)v[6]) * k1.z);
  r[7] = (short)f2bfb(b2f((unsigned short)v[7]) * k1.w);
  *(s16x8*)((short*)qn + i) = r;
}

// GLU over a chunk: out[tok][d] = c[tok][d] * sigmoid(c[tok][512+d])
__global__ __launch_bounds__(256)
void glu_k(const __hip_bfloat16* __restrict__ c, __hip_bfloat16* __restrict__ out)
{
  const size_t i = ((size_t)blockIdx.x * 256 + threadIdx.x) * 8;
  const size_t tok = i >> 9;
  const int d = (int)(i & 511);
  const short* row = (const short*)c + tok * 1024;
  const s16x8 a8 = *(const s16x8*)(row + d);
  const s16x8 g8 = *(const s16x8*)(row + 512 + d);
  s16x8 r;
#pragma unroll
  for (int j = 0; j < 8; ++j) {
    const float a = b2f((unsigned short)a8[j]);
    const float g = b2f((unsigned short)g8[j]);
    r[j] = (short)f2bfb(a * sigm(g));
  }
  *(s16x8*)((short*)out + i) = r;
}

// transpose depthwise weights [D][KW] -> [KW][D] (tiny, once per call)
__global__ __launch_bounds__(256)
void dwt_k(const float* __restrict__ dww, float* __restrict__ dwt)
{
  const int i = blockIdx.x * 256 + threadIdx.x;
  if (i >= KW * TD) return;
  const int j = i / TD, d = i % TD;
  dwt[i] = dww[d * KW + j];
}

// ---------------------------------------------------------------------------
// depthwise conv(K=31, pad 15) + bias + LN + swish -> bf16.
// Block = (batch b, tile of CT=8 tokens); thread owns channels d and d+256.
// Weights from transposed dwt[KW][D] (coalesced); inputs+weights held in regs,
// all statically indexed (full unroll).
// ---------------------------------------------------------------------------
__global__ __launch_bounds__(256)
void conv_ln_swish2(const __hip_bfloat16* __restrict__ gin, const float* __restrict__ dwt,
                    const float* __restrict__ dwb, const float* __restrict__ lg,
                    const float* __restrict__ lb, __hip_bfloat16* __restrict__ out)
{
  const int b = blockIdx.x / (TT / CT);
  const int t0 = (blockIdx.x % (TT / CT)) * CT;
  const int tid = threadIdx.x;
  const int w = tid >> 6, l = tid & 63;

  float a[2][CT];
#pragma unroll
  for (int hh = 0; hh < 2; ++hh) {
    const int d = tid + hh * 256;
    float wreg[KW];
#pragma unroll
    for (int j = 0; j < KW; ++j) wreg[j] = dwt[j * TD + d];
    const short* base = (const short*)gin + (size_t)b * TT * TD + d;
    float xv[CT + KW - 1];
#pragma unroll
    for (int r = 0; r < CT + KW - 1; ++r) {
      const int tt = t0 + r - 15;
      xv[r] = (tt >= 0 && tt < TT) ? b2f((unsigned short)base[(size_t)tt * TD]) : 0.f;
    }
    const float bv = dwb[d];
#pragma unroll
    for (int t = 0; t < CT; ++t) {
      float acc = bv;
#pragma unroll
      for (int j = 0; j < KW; ++j) acc += xv[t + j] * wreg[j];
      a[hh][t] = acc;
    }
  }

  // per-token LN stats over 512 channels (thread holds 2 channels x CT tokens)
  __shared__ float red[2][4][CT];
#pragma unroll
  for (int t = 0; t < CT; ++t) {
    float ps = a[0][t] + a[1][t];
    float pq = a[0][t] * a[0][t] + a[1][t] * a[1][t];
#pragma unroll
    for (int o = 32; o > 0; o >>= 1) { ps += __shfl_xor(ps, o); pq += __shfl_xor(pq, o); }
    if (l == 0) { red[0][w][t] = ps; red[1][w][t] = pq; }
  }
  __syncthreads();
  float mean[CT], rs[CT];
#pragma unroll
  for (int t = 0; t < CT; ++t) {
    const float s = red[0][0][t] + red[0][1][t] + red[0][2][t] + red[0][3][t];
    const float q = red[1][0][t] + red[1][1][t] + red[1][2][t] + red[1][3][t];
    mean[t] = s * (1.f / TD);
    rs[t] = rsqrtf(q * (1.f / TD) - mean[t] * mean[t] + 1e-5f);
  }
#pragma unroll
  for (int hh = 0; hh < 2; ++hh) {
    const int d = tid + hh * 256;
    const float gv = lg[d], bv = lb[d];
#pragma unroll
    for (int t = 0; t < CT; ++t) {
      const float y = (a[hh][t] - mean[t]) * rs[t] * gv + bv;
      out[((size_t)b * TT + t0 + t) * TD + d] = __float2bfloat16(y * sigm(y));
    }
  }
}

// f32 -> bf16 cast, 8 elems/thread
__global__ __launch_bounds__(256)
void cast8_k(const float* __restrict__ in, __hip_bfloat16* __restrict__ out, int n8)
{
  const int i = blockIdx.x * 256 + threadIdx.x;
  if (i >= n8) return;
  const float4 a = ((const float4*)in)[2 * i];
  const float4 b = ((const float4*)in)[2 * i + 1];
  s16x8 r;
  r[0] = (short)f2bfb(a.x); r[1] = (short)f2bfb(a.y);
  r[2] = (short)f2bfb(a.z); r[3] = (short)f2bfb(a.w);
  r[4] = (short)f2bfb(b.x); r[5] = (short)f2bfb(b.y);
  r[6] = (short)f2bfb(b.z); r[7] = (short)f2bfb(b.w);
  ((s16x8*)out)[i] = r;
}

extern "C" void kernel_launch(void* const* d_in, const int* in_sizes, int n_in,
                              void* d_out, int out_size, void* d_ws, size_t ws_size,
                              hipStream_t stream)
{
  const float* x      = (const float*)d_in[0];
  const float* ln1_g  = (const float*)d_in[1];
  const float* ln1_b  = (const float*)d_in[2];
  const float* ff1_w1 = (const float*)d_in[3];
  const float* ff1_b1 = (const float*)d_in[4];
  const float* ff1_w2 = (const float*)d_in[5];
  const float* ff1_b2 = (const float*)d_in[6];
  const float* lna_g  = (const float*)d_in[7];
  const float* lna_b  = (const float*)d_in[8];
  const float* qkv_w  = (const float*)d_in[9];
  const float* qkv_b  = (const float*)d_in[10];
  const float* aow    = (const float*)d_in[11];
  const float* aob    = (const float*)d_in[12];
  const float* lnc_g  = (const float*)d_in[13];
  const float* lnc_b  = (const float*)d_in[14];
  const float* pw1_w  = (const float*)d_in[15];
  const float* pw1_b  = (const float*)d_in[16];
  const float* dw_w   = (const float*)d_in[17];
  const float* dw_b   = (const float*)d_in[18];
  const float* lncn_g = (const float*)d_in[19];
  const float* lncn_b = (const float*)d_in[20];
  const float* pw2_w  = (const float*)d_in[21];
  const float* pw2_b  = (const float*)d_in[22];
  const float* ln2_g  = (const float*)d_in[23];
  const float* ln2_b  = (const float*)d_in[24];
  const float* ff2_w1 = (const float*)d_in[25];
  const float* ff2_b1 = (const float*)d_in[26];
  const float* ff2_w2 = (const float*)d_in[27];
  const float* ff2_b2 = (const float*)d_in[28];
  const float* lno_g  = (const float*)d_in[29];
  const float* lno_b  = (const float*)d_in[30];
  (void)in_sizes; (void)n_in; (void)out_size;

  // Residual stream lives in d_out (f32, exactly B*T*D); final LN is in-place.
  float* res = (float*)d_out;

  char* ws = (char*)d_ws;
  size_t off = 0;
  auto alloc = [&](size_t bytes) {
    char* p = ws + off;
    off = (off + bytes + 255) & ~(size_t)255;
    return p;
  };

  __hip_bfloat16* wff1a = (__hip_bfloat16*)alloc((size_t)TDFF * TD * 2);
  __hip_bfloat16* wff1b = (__hip_bfloat16*)alloc((size_t)TD * TDFF * 2);
  __hip_bfloat16* wqkv  = (__hip_bfloat16*)alloc((size_t)3 * TD * TD * 2);
  __hip_bfloat16* wao   = (__hip_bfloat16*)alloc((size_t)TD * TD * 2);
  __hip_bfloat16* wpw1  = (__hip_bfloat16*)alloc((size_t)2 * TD * TD * 2);
  __hip_bfloat16* wpw2  = (__hip_bfloat16*)alloc((size_t)TD * TD * 2);
  __hip_bfloat16* wff2a = (__hip_bfloat16*)alloc((size_t)TDFF * TD * 2);
  __hip_bfloat16* wff2b = (__hip_bfloat16*)alloc((size_t)TD * TDFF * 2);
  __hip_bfloat16* h     = (__hip_bfloat16*)alloc((size_t)NTOK * TD * 2);     // 32MB
  __hip_bfloat16* big   = (__hip_bfloat16*)alloc((size_t)CH * TDFF * 2);     // 32MB chunk buf
  float*          kv    = (float*)alloc((size_t)TB * TD * 4);
  float*          kvp   = (float*)alloc((size_t)TB * 32 * TD * 4);
  float*          dwt   = (float*)alloc((size_t)KW * TD * 4);

  if (ws_size < off) return;   // interpretable failure instead of a page fault

  const dim3 blk(256);
  const int M = NTOK;

  auto cast = [&](const float* src, __hip_bfloat16* dst, int n) {
    cast8_k<<<(n / 8 + 255) / 256, blk, 0, stream>>>(src, dst, n / 8);
  };
  cast(ff1_w1, wff1a, TDFF * TD);
  cast(ff1_w2, wff1b, TD * TDFF);
  cast(qkv_w,  wqkv,  3 * TD * TD);
  cast(aow,    wao,   TD * TD);
  cast(pw1_w,  wpw1,  2 * TD * TD);
  cast(pw2_w,  wpw2,  TD * TD);
  cast(ff2_w1, wff2a, TDFF * TD);
  cast(ff2_w2, wff2b, TD * TDFF);
  dwt_k<<<(KW * TD + 255) / 256, blk, 0, stream>>>(dw_w, dwt);

  // ---- FF1 (half-step): res = x + 0.5*ffn(ln1(x)) ----
  ln_k<0><<<M / 4, blk, 0, stream>>>(x, ln1_g, ln1_b, h);
  for (int c = 0; c < NCHUNK; ++c) {
    const size_t o5 = (size_t)c * CH * TD;
    gemm_bt<1><<<dim3(CH / 128, TDFF / 128), blk, 0, stream>>>(
        h + o5, wff1a, ff1_b1, nullptr, nullptr, big, TDFF, TD, 0.f);
    gemm_bt<2><<<dim3(CH / 128, TD / 128), blk, 0, stream>>>(
        big, wff1b, ff1_b2, x + o5, res + o5, nullptr, TD, TDFF, 0.5f);
  }

  // ---- Hydra attention ----
  ln_k<0><<<M / 4, blk, 0, stream>>>(res, lna_g, lna_b, h);
  for (int c = 0; c < NCHUNK; ++c) {
    const size_t o5 = (size_t)c * CH * TD;
    gemm_bt<0><<<dim3(CH / 128, 3 * TD / 128), blk, 0, stream>>>(
        h + o5, wqkv, qkv_b, nullptr, nullptr, big, 3 * TD, TD, 0.f);
    hydra_pass1<<<dim3(CH / TT, 32), blk, 0, stream>>>(big, h + o5, kvp, c * (CH / TT));
  }
  kv_reduce<<<(TB * TD) / 256, blk, 0, stream>>>(kvp, kv);
  qscale_k<<<(M * (TD / 8)) / 256, blk, 0, stream>>>(h, kv);
  gemm_bt<2><<<dim3(M / 128, TD / 128), blk, 0, stream>>>(
      h, wao, aob, res, res, nullptr, TD, TD, 1.f);

  // ---- Conv module ----
  ln_k<0><<<M / 4, blk, 0, stream>>>(res, lnc_g, lnc_b, h);
  for (int c = 0; c < NCHUNK; ++c) {
    const size_t o5 = (size_t)c * CH * TD;
    gemm_bt<0><<<dim3(CH / 128, 2 * TD / 128), blk, 0, stream>>>(
        h + o5, wpw1, pw1_b, nullptr, nullptr, big, 2 * TD, TD, 0.f);
    glu_k<<<(CH * (TD / 8)) / 256, blk, 0, stream>>>(big, h + o5);
  }
  // conv input h (full M), output into big (M x D bf16 = same 32MB)
  conv_ln_swish2<<<TB * (TT / CT), blk, 0, stream>>>(h, dwt, dw_b, lncn_g, lncn_b, big);
  gemm_bt<2><<<dim3(M / 128, TD / 128), blk, 0, stream>>>(
      big, wpw2, pw2_b, res, res, nullptr, TD, TD, 1.f);

  // ---- FF2 (half-step) ----
  ln_k<0><<<M / 4, blk, 0, stream>>>(res, ln2_g, ln2_b, h);
  for (int c = 0; c < NCHUNK; ++c) {
    const size_t o5 = (size_t)c * CH * TD;
    gemm_bt<1><<<dim3(CH / 128, TDFF / 128), blk, 0, stream>>>(
        h + o5, wff2a, ff2_b1, nullptr, nullptr, big, TDFF, TD, 0.f);
    gemm_bt<2><<<dim3(CH / 128, TD / 128), blk, 0, stream>>>(
        big, wff2b, ff2_b2, res + o5, res + o5, nullptr, TD, TDFF, 0.5f);
  }

  // ---- final LN (in-place on d_out) ----
  ln_k<1><<<M / 4, blk, 0, stream>>>(res, lno_g, lno_b, res);
}